// Round 7
// baseline (306.404 us; speedup 1.0000x reference)
//
#include <hip/hip_runtime.h>
#include <hip/hip_bf16.h>

// ---------------------------------------------------------------------------
// DatasetScoreMatchingLoss — emulates np's fp32 sequential segment_sum via
// quantized contributions c_i = u*rint(x_i/u), u = ulp of the running-prefix
// binade, predicted per chunk by a linear model (exclusive chunk prefix +
// mean rate). Round 11: three rounds proved hipcc sinks any C-level
// prefetch (VGPR 40-84, ~870cy = 1 exposed HBM latency per iteration).
// Fix: EXPLICIT ASM LOAD PIPELINE (guide T3/T4, counted vmcnt):
//   - loads issued via asm volatile global_load_* (compiler cannot sink);
//   - consumed after asm s_waitcnt vmcnt(N) + sched_barrier(0) (rule #18);
//   - pass1: 4-slot ring, 3 groups in flight, vmcnt(12) steady;
//   - pass2: 6-slot ring, 5 in flight, vmcnt(15) steady.
// vmcnt retires in-order; target group is always the oldest load group ->
// counted waits never under-wait (stores/override loads are younger).
// Override branch still drains (compiler vmcnt(0) on tbl2 loads, ~39% of
// wave-iters) — accepted. Per-thread element order unchanged -> bit-identical.
// ---------------------------------------------------------------------------

#define TBL   65536u
#define TBLM  (TBL - 1u)
#define NGR   12            // actual group ids in [0,12)
#define NBK   24            // 12 groups x 2 labels
#define NCOL  25            // +1 dummy column (invalid / merged-away)
#define CCOL  26            // u16 count columns (incl dummy, padded)
#define NTHR  256
#define CHUNK 16384
#define ITER  (CHUNK / 4 / NTHR)
#define MINC  10.0

static_assert(ITER == 16, "pipeline is hand-unrolled for ITER==16");

__device__ __forceinline__ unsigned hash_idx(unsigned idx) {
    return (idx * 2654435761u) & TBLM;
}

// --- asm load helpers: issue now, data valid only after explicit vmcnt ------
__device__ __forceinline__ float4 gldf4(const float4* p) {
    float4 r;
    asm volatile("global_load_dwordx4 %0, %1, off"
                 : "=v"(r) : "v"(p) : "memory");
    return r;
}
__device__ __forceinline__ int4 gldi4(const int4* p) {
    int4 r;
    asm volatile("global_load_dwordx4 %0, %1, off"
                 : "=v"(r) : "v"(p) : "memory");
    return r;
}
__device__ __forceinline__ unsigned gldu(const unsigned* p) {
    unsigned r;
    asm volatile("global_load_dword %0, %1, off"
                 : "=v"(r) : "v"(p) : "memory");
    return r;
}
// wait until <=N vector-memory ops outstanding, then fence the scheduler
#define VMW(N) do { asm volatile("s_waitcnt vmcnt(" #N ")" ::: "memory"); \
                    __builtin_amdgcn_sched_barrier(0); } while (0)

// --- Phase 1: vote for last writer (max batch pos) + mark bitmap ------------
__global__ void k_vote(const int* __restrict__ indices,
                       unsigned long long* __restrict__ table,
                       unsigned* __restrict__ bitmap, int B) {
    int b = blockIdx.x * blockDim.x + threadIdx.x;
    if (b >= B) return;
    unsigned idx = (unsigned)indices[b];
    atomicOr(&bitmap[idx >> 5], 1u << (idx & 31u));
    unsigned long long key = ((unsigned long long)(idx + 1u)) << 32;
    unsigned long long val = key | (unsigned long long)(unsigned)b;
    unsigned slot = hash_idx(idx);
    for (;;) {
        unsigned long long prev = atomicCAS(&table[slot], 0ULL, val);
        if (prev == 0ULL) return;
        if ((prev >> 32) == (unsigned long long)(idx + 1u)) {
            atomicMax(&table[slot], val);
            return;
        }
        slot = (slot + 1u) & TBLM;
    }
}

// --- Phase 1.5: expand winners into single-load records ---------------------
__global__ void k_resolve(const unsigned long long* __restrict__ table,
                          const float* __restrict__ probs,
                          const int* __restrict__ labels,
                          const int* __restrict__ groups,
                          float4* __restrict__ tbl2) {
    int s = blockIdx.x * blockDim.x + threadIdx.x;
    unsigned long long e = table[s];
    unsigned hi = (unsigned)(e >> 32);
    float4 r = make_float4(0.f, 0.f, 0.f, 0.f);
    if (hi) {
        int b = (int)(e & 0xffffffffu);
        r.x = probs[b];
        r.y = __int_as_float(labels[b]);
        r.z = __int_as_float(groups[b]);
        r.w = __uint_as_float(hi);
    }
    tbl2[s] = r;
}

// Resolve full override record (pass1; rare: ~32K/16.7M elements).
__device__ __forceinline__ void apply_ovr(int idx, float& s, int& l, int& g,
        const float4* __restrict__ tbl2) {
    unsigned slot = hash_idx((unsigned)idx);
    unsigned hi = (unsigned)idx + 1u;
    for (;;) {
        float4 r = tbl2[slot];
        if (__float_as_uint(r.w) == hi) {
            s = r.x; l = __float_as_int(r.y); g = __float_as_int(r.z);
            return;
        }
        slot = (slot + 1u) & TBLM;
    }
}

// Resolve score-only override (pass2; bucket already baked into stream).
__device__ __forceinline__ float ovr_s(int idx,
        const float4* __restrict__ tbl2) {
    unsigned slot = hash_idx((unsigned)idx);
    unsigned hi = (unsigned)idx + 1u;
    for (;;) {
        float4 r = tbl2[slot];
        if (__float_as_uint(r.w) == hi) return r.x;
        slot = (slot + 1u) & TBLM;
    }
}

// --- quad processing for pass1: plain read/add/write rows + bucket stream ---
__device__ __forceinline__ void quad_p1(float* __restrict__ row,
        unsigned* __restrict__ bstr32,
        float4 s4, int4 l4, int4 g4, unsigned bits, int v,
        const float4* __restrict__ tbl2) {
    float ss[4] = {s4.x, s4.y, s4.z, s4.w};
    int   ll[4] = {l4.x, l4.y, l4.z, l4.w};
    int   gg[4] = {g4.x, g4.y, g4.z, g4.w};
    if (bits & 0xFu) {                       // one branch per quad (rare)
#pragma unroll
        for (int e = 0; e < 4; ++e)
            if ((bits >> e) & 1u)
                apply_ovr((v << 2) + e, ss[e], ll[e], gg[e], tbl2);
    }
    float val[4]; int bkt[4];
#pragma unroll
    for (int e = 0; e < 4; ++e) {
        bool valid = (ss[e] == ss[e]) && ((unsigned)ll[e] < 2u) &&
                     ((unsigned)gg[e] < (unsigned)NGR);
        bkt[e] = valid ? (gg[e] * 2 + ll[e]) : NBK;
        val[e] = valid ? ss[e] : 0.f;
    }
    // emit per-element bucket bytes (pre-merge) for pass2
    bstr32[v] = (unsigned)bkt[0] | ((unsigned)bkt[1] << 8) |
                ((unsigned)bkt[2] << 16) | ((unsigned)bkt[3] << 24);
    // merge intra-quad duplicates so 4 reads can batch before 4 writes
#define MRG(i, j) { bool m_ = (bkt[i] == bkt[j]); \
                    val[i] += m_ ? val[j] : 0.f;  \
                    bkt[j] = m_ ? NBK : bkt[j];   \
                    val[j] = m_ ? 0.f : val[j]; }
    MRG(0,1) MRG(0,2) MRG(0,3) MRG(1,2) MRG(1,3) MRG(2,3)
#undef MRG
    float a0 = row[bkt[0]], a1 = row[bkt[1]], a2 = row[bkt[2]], a3 = row[bkt[3]];
    row[bkt[0]] = a0 + val[0];
    row[bkt[1]] = a1 + val[1];
    row[bkt[2]] = a2 + val[2];
    row[bkt[3]] = a3 + val[3];
}

// --- Phase 2: per-chunk fp32 bucket sums (LDS slots) + bucket stream --------
__global__ __launch_bounds__(NTHR, 4) void k_pass1(
        const float* __restrict__ sb, const int* __restrict__ lb,
        const int* __restrict__ gb, const unsigned* __restrict__ bitmap,
        const float4* __restrict__ tbl2,
        float* __restrict__ bsum, unsigned char* __restrict__ bstream,
        int n, int nblk) {
    __shared__ float s_acc[NTHR * NCOL];      // 25.6 KB
    int tid = threadIdx.x, blk = blockIdx.x;
    for (int i = tid; i < NTHR * NCOL; i += NTHR) s_acc[i] = 0.f;
    __syncthreads();
    float* row = &s_acc[tid * NCOL];
    unsigned* bstr32 = (unsigned*)bstream;
    int vbase = (blk * CHUNK) >> 2, nv = n >> 2;
    if (vbase + (CHUNK >> 2) <= nv) {
        // full chunk: asm pipeline, 4 slots, 3 groups in flight
        int v0 = vbase + tid;
        unsigned sh = (unsigned)((v0 & 7) * 4);   // uniform per thread
        float4 S[4]; int4 L[4], G[4]; unsigned Bm[4];
#define P1_ISSUE(it, sl) { int v_ = v0 + (it) * NTHR;              \
        S[sl]  = gldf4((const float4*)sb + v_);                    \
        L[sl]  = gldi4((const int4*)lb + v_);                      \
        G[sl]  = gldi4((const int4*)gb + v_);                      \
        Bm[sl] = gldu(bitmap + (v_ >> 3)); }
#define P1_COMP(t, sl) quad_p1(row, bstr32, S[sl], L[sl], G[sl],   \
                               Bm[sl] >> sh, v0 + (t) * NTHR, tbl2);
        P1_ISSUE(0, 0) P1_ISSUE(1, 1) P1_ISSUE(2, 2)
        P1_ISSUE(3, 3)  VMW(12); P1_COMP(0, 0)
        P1_ISSUE(4, 0)  VMW(12); P1_COMP(1, 1)
        P1_ISSUE(5, 1)  VMW(12); P1_COMP(2, 2)
        P1_ISSUE(6, 2)  VMW(12); P1_COMP(3, 3)
        P1_ISSUE(7, 3)  VMW(12); P1_COMP(4, 0)
        P1_ISSUE(8, 0)  VMW(12); P1_COMP(5, 1)
        P1_ISSUE(9, 1)  VMW(12); P1_COMP(6, 2)
        P1_ISSUE(10, 2) VMW(12); P1_COMP(7, 3)
        P1_ISSUE(11, 3) VMW(12); P1_COMP(8, 0)
        P1_ISSUE(12, 0) VMW(12); P1_COMP(9, 1)
        P1_ISSUE(13, 1) VMW(12); P1_COMP(10, 2)
        P1_ISSUE(14, 2) VMW(12); P1_COMP(11, 3)
        P1_ISSUE(15, 3) VMW(12); P1_COMP(12, 0)
        VMW(8);  P1_COMP(13, 1)
        VMW(4);  P1_COMP(14, 2)
        VMW(0);  P1_COMP(15, 3)
#undef P1_ISSUE
#undef P1_COMP
    } else {
        for (int it = 0; it < ITER; ++it) {
            int v = vbase + it * NTHR + tid;
            if (v >= nv) break;
            float4 s4 = ((const float4*)sb)[v];
            int4   l4 = ((const int4*)lb)[v];
            int4   g4 = ((const int4*)gb)[v];
            unsigned bits = bitmap[v >> 3] >> ((v & 7) * 4);
            quad_p1(row, bstr32, s4, l4, g4, bits, v, tbl2);
        }
    }
    // scalar tail (n % 4) — last block only
    if (blk == nblk - 1) {
        for (int i = (nv << 2) + tid; i < n; i += NTHR) {
            float s = sb[i]; int l = lb[i], g = gb[i];
            if ((bitmap[i >> 5] >> (i & 31)) & 1u)
                apply_ovr(i, s, l, g, tbl2);
            bool valid = (s == s) && ((unsigned)l < 2u) && ((unsigned)g < (unsigned)NGR);
            int bk = valid ? (g * 2 + l) : NBK;
            bstream[i] = (unsigned char)bk;
            row[bk] += valid ? s : 0.f;
        }
    }
    __syncthreads();
    if (tid < NBK * 8) {
        int bkt = tid >> 3, sub = tid & 7;
        float sm = 0.f;
        for (int j = 0; j < 32; ++j) sm += s_acc[(sub * 32 + j) * NCOL + bkt];
        for (int d = 4; d >= 1; d >>= 1) sm += __shfl_down(sm, d, 8);
        if (!sub) bsum[bkt * nblk + blk] = sm;
    }
}

// --- Phase 2.5: exclusive scan, one block per bucket (fp64) -----------------
__global__ void k_scan(const float* __restrict__ bsum,
                       float* __restrict__ bpref, int nblk) {
    __shared__ double sc[NTHR];
    int t = threadIdx.x, k = blockIdx.x;
    const float* src = bsum  + (size_t)k * nblk;
    float*       dst = bpref + (size_t)k * nblk;
    double carry = 0.0;
    for (int s0 = 0; s0 < nblk; s0 += 4 * NTHR) {
        int i0 = s0 + 4 * t;
        float x0 = (i0 + 0 < nblk) ? src[i0 + 0] : 0.f;
        float x1 = (i0 + 1 < nblk) ? src[i0 + 1] : 0.f;
        float x2 = (i0 + 2 < nblk) ? src[i0 + 2] : 0.f;
        float x3 = (i0 + 3 < nblk) ? src[i0 + 3] : 0.f;
        double p0 = (double)x0, p1 = p0 + x1, p2 = p1 + x2, tot = p2 + x3;
        sc[t] = tot;
        __syncthreads();
        for (int st = 1; st < NTHR; st <<= 1) {
            double a = (t >= st) ? sc[t - st] : 0.0;
            __syncthreads();
            sc[t] += a;
            __syncthreads();
        }
        double excl = carry + sc[t] - tot;
        if (i0 + 0 < nblk) dst[i0 + 0] = (float)excl;
        if (i0 + 1 < nblk) dst[i0 + 1] = (float)(excl + p0);
        if (i0 + 2 < nblk) dst[i0 + 2] = (float)(excl + p1);
        if (i0 + 3 < nblk) dst[i0 + 3] = (float)(excl + p2);
        double bt = sc[NTHR - 1];
        __syncthreads();
        carry += bt;
    }
}

__device__ __forceinline__ double aload_d(const double* p) {
    unsigned long long u = __hip_atomic_load((const unsigned long long*)p,
                              __ATOMIC_RELAXED, __HIP_MEMORY_SCOPE_AGENT);
    return __longlong_as_double((long long)u);
}

// --- quad processing for pass2: bucket bytes + score stream -----------------
// c_sum in float rows (order-preserving), counts in u16 rows (exact ints).
__device__ __forceinline__ void quad_p2(float* __restrict__ row,
        unsigned short* __restrict__ crow,
        const float2* __restrict__ s_model,
        float4 s4, unsigned b4, unsigned obits, int v, int base,
        const float4* __restrict__ tbl2) {
    float ss[4] = {s4.x, s4.y, s4.z, s4.w};
    if (obits & 0xFu) {                      // one branch per quad (rare)
#pragma unroll
        for (int e = 0; e < 4; ++e)
            if ((obits >> e) & 1u) ss[e] = ovr_s((v << 2) + e, tbl2);
    }
    float cv[4]; int bkt[4], cn[4];
#pragma unroll
    for (int e = 0; e < 4; ++e) {
        int idx = (v << 2) + e;
        int bk = (int)((b4 >> (8 * e)) & 0xFFu);
        float s = ss[e];
        float2 m = s_model[bk];
        float S = fmaf(m.y, (float)(idx - base), m.x);
        float T = S + s;                          // post-add binade probe
        unsigned ue = __float_as_uint(T) & 0x7f800000u;
        float c;
        if (ue < (24u << 23)) c = s;              // tiny/zero prefix
        else {
            unsigned ub = ue - (23u << 23);       // u = ulp = 2^(e-150)
            float u    = __uint_as_float(ub);
            float uinv = __uint_as_float((254u << 23) - ub);
            c = u * rintf(s * uinv);
        }
        bool valid = bk < NBK;
        bkt[e] = bk;
        cv[e] = valid ? c : 0.f;
        cn[e] = valid ? 1 : 0;
    }
#define MRG(i, j) { bool m_ = (bkt[i] == bkt[j]); \
                    cv[i] += m_ ? cv[j] : 0.f;    \
                    cn[i] += m_ ? cn[j] : 0;      \
                    bkt[j] = m_ ? NBK : bkt[j];   \
                    cv[j] = m_ ? 0.f : cv[j];     \
                    cn[j] = m_ ? 0 : cn[j]; }
    MRG(0,1) MRG(0,2) MRG(0,3) MRG(1,2) MRG(1,3) MRG(2,3)
#undef MRG
    float a0 = row[bkt[0]], a1 = row[bkt[1]], a2 = row[bkt[2]], a3 = row[bkt[3]];
    row[bkt[0]] = a0 + cv[0];
    row[bkt[1]] = a1 + cv[1];
    row[bkt[2]] = a2 + cv[2];
    row[bkt[3]] = a3 + cv[3];
    unsigned short c0 = crow[bkt[0]], c1 = crow[bkt[1]],
                   c2 = crow[bkt[2]], c3 = crow[bkt[3]];
    crow[bkt[0]] = (unsigned short)(c0 + cn[0]);
    crow[bkt[1]] = (unsigned short)(c1 + cn[1]);
    crow[bkt[2]] = (unsigned short)(c2 + cn[2]);
    crow[bkt[3]] = (unsigned short)(c3 + cn[3]);
}

// --- Phase 3: quantized contributions (float rows) + counts (u16 rows) ------
// Last block to finish runs the fp64 epilogue and writes out[0].
__global__ __launch_bounds__(NTHR, 4) void k_pass2(
        const float* __restrict__ sb,
        const unsigned char* __restrict__ bstream,
        const unsigned* __restrict__ bitmap,
        const float4* __restrict__ tbl2,
        const float* __restrict__ bsum, const float* __restrict__ bpref,
        double* __restrict__ acc_sum, double* __restrict__ acc_cnt,
        unsigned* __restrict__ done, float* __restrict__ out,
        int n, int nblk) {
    __shared__ float s_accv[NTHR * NCOL];         // 25.6 KB c_sum
    __shared__ unsigned short s_cnt[NTHR * CCOL]; // 13.3 KB counts
    __shared__ float2 s_model[NCOL];              // (excl_prefix, rate)
    int tid = threadIdx.x, blk = blockIdx.x;
    for (int i = tid; i < NTHR * NCOL; i += NTHR) s_accv[i] = 0.f;
    for (int i = tid; i < NTHR * CCOL; i += NTHR) s_cnt[i] = 0;
    if (tid < NBK)
        s_model[tid] = make_float2(bpref[tid * nblk + blk],
                                   bsum[tid * nblk + blk] * (1.0f / CHUNK));
    if (tid == NBK) s_model[NBK] = make_float2(0.f, 0.f);
    __syncthreads();
    float* row = &s_accv[tid * NCOL];
    unsigned short* crow = &s_cnt[tid * CCOL];
    const unsigned* bstr32 = (const unsigned*)bstream;
    int base = blk * CHUNK;
    int vbase = base >> 2, nv = n >> 2;
    if (vbase + (CHUNK >> 2) <= nv) {
        // full chunk: asm pipeline, 6 slots, 5 groups in flight
        int v0 = vbase + tid;
        unsigned sh = (unsigned)((v0 & 7) * 4);   // uniform per thread
        float4 S[6]; unsigned K[6], Bm[6];
#define P2_ISSUE(it, sl) { int v_ = v0 + (it) * NTHR;              \
        S[sl]  = gldf4((const float4*)sb + v_);                    \
        K[sl]  = gldu(bstr32 + v_);                                \
        Bm[sl] = gldu(bitmap + (v_ >> 3)); }
#define P2_COMP(t, sl) quad_p2(row, crow, s_model, S[sl], K[sl],   \
                               Bm[sl] >> sh, v0 + (t) * NTHR, base, tbl2);
        P2_ISSUE(0, 0) P2_ISSUE(1, 1) P2_ISSUE(2, 2)
        P2_ISSUE(3, 3) P2_ISSUE(4, 4)
        P2_ISSUE(5, 5)  VMW(15); P2_COMP(0, 0)
        P2_ISSUE(6, 0)  VMW(15); P2_COMP(1, 1)
        P2_ISSUE(7, 1)  VMW(15); P2_COMP(2, 2)
        P2_ISSUE(8, 2)  VMW(15); P2_COMP(3, 3)
        P2_ISSUE(9, 3)  VMW(15); P2_COMP(4, 4)
        P2_ISSUE(10, 4) VMW(15); P2_COMP(5, 5)
        P2_ISSUE(11, 5) VMW(15); P2_COMP(6, 0)
        P2_ISSUE(12, 0) VMW(15); P2_COMP(7, 1)
        P2_ISSUE(13, 1) VMW(15); P2_COMP(8, 2)
        P2_ISSUE(14, 2) VMW(15); P2_COMP(9, 3)
        P2_ISSUE(15, 3) VMW(15); P2_COMP(10, 4)
        VMW(12); P2_COMP(11, 5)
        VMW(9);  P2_COMP(12, 0)
        VMW(6);  P2_COMP(13, 1)
        VMW(3);  P2_COMP(14, 2)
        VMW(0);  P2_COMP(15, 3)
#undef P2_ISSUE
#undef P2_COMP
    } else {
        for (int it = 0; it < ITER; ++it) {
            int v = vbase + it * NTHR + tid;
            if (v >= nv) break;
            float4 s4 = ((const float4*)sb)[v];
            unsigned b4 = bstr32[v];
            unsigned bits = bitmap[v >> 3] >> ((v & 7) * 4);
            quad_p2(row, crow, s_model, s4, b4, bits, v, base, tbl2);
        }
    }
    if (blk == nblk - 1) {                            // scalar tail
        for (int i = (nv << 2) + tid; i < n; i += NTHR) {
            float s = sb[i];
            int bk = (int)bstream[i];
            if ((bitmap[i >> 5] >> (i & 31)) & 1u)
                s = ovr_s(i, tbl2);
            float2 m = s_model[bk];
            float S = fmaf(m.y, (float)(i - base), m.x);
            float T = S + s;
            unsigned ue = __float_as_uint(T) & 0x7f800000u;
            float c;
            if (ue < (24u << 23)) c = s;
            else {
                unsigned ub = ue - (23u << 23);
                float u    = __uint_as_float(ub);
                float uinv = __uint_as_float((254u << 23) - ub);
                c = u * rintf(s * uinv);
            }
            bool valid = bk < NBK;
            row[bk] += valid ? c : 0.f;
            crow[bk] = (unsigned short)(crow[bk] + (valid ? 1 : 0));
        }
    }
    __syncthreads();
    if (tid < NBK * 8) {
        int bkt = tid >> 3, sub = tid & 7;
        float sm = 0.f; unsigned cc = 0;
        for (int j = 0; j < 32; ++j) {
            int t2 = sub * 32 + j;
            sm += s_accv[t2 * NCOL + bkt];
            cc += s_cnt[t2 * CCOL + bkt];
        }
        for (int d = 4; d >= 1; d >>= 1) {
            sm += __shfl_down(sm, d, 8);
            cc += __shfl_down(cc, d, 8);
        }
        if (!sub) {
            atomicAdd(&acc_sum[bkt], (double)sm);
            atomicAdd(&acc_cnt[bkt], (double)cc);
        }
    }
    __syncthreads();
    if (tid == 0) {
        __threadfence();
        unsigned r = __hip_atomic_fetch_add(done, 1u, __ATOMIC_ACQ_REL,
                                            __HIP_MEMORY_SCOPE_AGENT);
        if (r == (unsigned)(gridDim.x - 1)) {         // last block: epilogue
            double var[2], nn[2];
            for (int l = 0; l < 2; ++l) {
                double avg[NGR];
                double ncnt = 0.0, s = 0.0;
                for (int g = 0; g < NGR; ++g) {
                    double c  = aload_d(&acc_cnt[g * 2 + l]);
                    double sm = aload_d(&acc_sum[g * 2 + l]);
                    double a = sm / fmax(c, 1.0);
                    avg[g] = a;
                    if (c >= MINC) { ncnt += 1.0; s += a; }
                }
                double mean = s / fmax(ncnt, 1.0), v = 0.0;
                for (int g = 0; g < NGR; ++g) {
                    double c = aload_d(&acc_cnt[g * 2 + l]);
                    if (c >= MINC) { double d = avg[g] - mean; v += d * d; }
                }
                var[l] = v / fmax(ncnt - 1.0, 1.0);
                nn[l] = ncnt;
            }
            bool p = nn[1] >= 2.0, q = nn[0] >= 2.0;
            double loss = (p && q) ? 0.5 * (var[1] + var[0])
                        : (p ? var[1] : (q ? var[0] : 0.0));
            out[0] = (float)loss;
        }
    }
}

extern "C" void kernel_launch(void* const* d_in, const int* in_sizes, int n_in,
                              void* d_out, int out_size, void* d_ws, size_t ws_size,
                              hipStream_t stream) {
    const float* probs   = (const float*)d_in[0];
    const int*   labels  = (const int*)d_in[1];
    const int*   groups  = (const int*)d_in[2];
    const int*   indices = (const int*)d_in[3];
    const float* sb      = (const float*)d_in[4];
    const int*   lb      = (const int*)d_in[5];
    const int*   gb      = (const int*)d_in[6];
    int B = in_sizes[0];
    int n = in_sizes[4];
    int nblk   = (n + CHUNK - 1) / CHUNK;
    int nwords = (n + 31) / 32;

    // ws layout: [zeroed: table | bitmap | acc_sum | acc_cnt | done]
    //            [unzeroed: tbl2 | bstream | bsum | bpref]
    char* ws = (char*)d_ws;
    size_t off = 0;
    unsigned long long* table = (unsigned long long*)(ws + off); off += (size_t)TBL * 8;
    unsigned* bitmap  = (unsigned*)(ws + off); off += (size_t)nwords * 4;
    off = (off + 15) & ~(size_t)15;
    double*   acc_sum = (double*)(ws + off);   off += NBK * 8;
    double*   acc_cnt = (double*)(ws + off);   off += NBK * 8;
    unsigned* done    = (unsigned*)(ws + off); off += 16;
    size_t zero_bytes = off;
    float4*   tbl2    = (float4*)(ws + off);   off += (size_t)TBL * 16;
    unsigned char* bstream = (unsigned char*)(ws + off);
    off += ((size_t)n + 15) & ~(size_t)15;
    float*    bsum    = (float*)(ws + off);    off += (size_t)nblk * NBK * 4;
    float*    bpref   = (float*)(ws + off);    off += (size_t)nblk * NBK * 4;

    hipMemsetAsync(d_ws, 0, zero_bytes, stream);

    dim3 bblk((B + NTHR - 1) / NTHR);
    hipLaunchKernelGGL(k_vote, bblk, dim3(NTHR), 0, stream,
                       indices, table, bitmap, B);
    hipLaunchKernelGGL(k_resolve, dim3(TBL / NTHR), dim3(NTHR), 0, stream,
                       table, probs, labels, groups, tbl2);
    hipLaunchKernelGGL(k_pass1, dim3(nblk), dim3(NTHR), 0, stream,
                       sb, lb, gb, bitmap, tbl2, bsum, bstream, n, nblk);
    hipLaunchKernelGGL(k_scan, dim3(NBK), dim3(NTHR), 0, stream,
                       bsum, bpref, nblk);
    hipLaunchKernelGGL(k_pass2, dim3(nblk), dim3(NTHR), 0, stream,
                       sb, bstream, bitmap, tbl2, bsum, bpref,
                       acc_sum, acc_cnt, done, (float*)d_out, n, nblk);
}